// Round 9
// baseline (185.964 us; speedup 1.0000x reference)
//
#include <hip/hip_runtime.h>

#define SEQ 128
#define BATCH 512
#define IN_DIM 128
#define HID 128

typedef float vf2 __attribute__((ext_vector_type(2)));

#define LOG2E 1.4426950408889634f
#define INV2PI 0.15915494309189535f

__device__ __forceinline__ float rcp_f(float x) { return __builtin_amdgcn_rcpf(x); }
// Guaranteed-native transcendentals (single VOP1 each).
__device__ __forceinline__ float exp2_f(float x) { float r; asm("v_exp_f32 %0, %1" : "=v"(r) : "v"(x)); return r; }
__device__ __forceinline__ float sin2pi_f(float x) { float r; asm("v_sin_f32 %0, %1" : "=v"(r) : "v"(x)); return r; }
__device__ __forceinline__ float cos2pi_f(float x) { float r; asm("v_cos_f32 %0, %1" : "=v"(r) : "v"(x)); return r; }
__device__ __forceinline__ float tanh_f(float x) {
  // tanh(x) = 1 - 2/(exp2(x*2log2e)+1)
  return 1.0f - 2.0f * rcp_f(exp2_f(x * 2.885390082f) + 1.0f);
}

template <int CTRL>
__device__ __forceinline__ float dpp_add(float s) {
  return s + __int_as_float(__builtin_amdgcn_mov_dpp(__float_as_int(s), CTRL, 0xF, 0xF, true));
}
template <int CTRL>
__device__ __forceinline__ float dpp_mov(float s) {
  return __int_as_float(__builtin_amdgcn_mov_dpp(__float_as_int(s), CTRL, 0xF, 0xF, true));
}
__device__ __forceinline__ float rdlane(float v, int src) {
  return __int_as_float(__builtin_amdgcn_readlane(__float_as_int(v), src));
}
// own + partner(lane^32), no select: permlane32_swap returns (lo-half data, hi-half data).
__device__ __forceinline__ float xor32_sum(float x) {
  unsigned xu = __float_as_uint(x);
  auto pr = __builtin_amdgcn_permlane32_swap(xu, xu, false, false);
  return __uint_as_float(pr[0]) + __uint_as_float(pr[1]);
}
// value from lane^16 (BitMode swizzle: xor=16, and=31; the documented wave-reduce pattern)
__device__ __forceinline__ float swz16(float x) {
  return __int_as_float(__builtin_amdgcn_ds_swizzle(__float_as_int(x), 0x401F));
}

// ONE WAVE per batch element.  ZERO LDS memory; no gate exchange, no bpermute.
//  * quad-gate rotation: lane's gate q = lane&3; each lane runs ONE TM chain
//    (gate q) -- the per-wire (c,s) are wave-uniform SGPRs so any lane can run
//    any gate.  ev values circulate inside the 4-lane quad via quad_perm DPP
//    (rot-1/2/3 = 0x39/0x4E/0x93), GEMM weights pre-indexed by rotation
//    distance k <-> gate (q+k)&3 at dims D0=2*lane, D0+1.  Cell update is
//    lane-local after a 2-level conditional un-rotate (16 cndmask).
//  * z-dot as reduce-scatter: part[w] = h/x contribution of dims D0,D0+1 to
//    wire w (x-part precomputed off-chain); butterfly xor32 (permlane32_swap)
//    -> xor16 (ds_swizzle) -> xor8 (DPP ROW_ROR:8) -> row8 DPP sum delivers
//    z[w] to lanes r=w (readlane broadcast unchanged).
//  * X load = one b64 per lane per step (coalesced), 2-deep counted-vmcnt
//    pipeline (R7) preserved.
__global__ __launch_bounds__(64) void qlstm_kernel(
    const float* __restrict__ X, const float* __restrict__ Wq, const float* __restrict__ bq,
    const float* __restrict__ pf, const float* __restrict__ pi_, const float* __restrict__ pg,
    const float* __restrict__ po, const float* __restrict__ Wf, const float* __restrict__ bf,
    const float* __restrict__ Wi, const float* __restrict__ bi, const float* __restrict__ Wg,
    const float* __restrict__ bg, const float* __restrict__ Wo, const float* __restrict__ bo,
    float* __restrict__ out)
{
  const int lane = threadIdx.x;
  const int r = lane >> 3;                       // wire landing slot (z[r] ends here)
  const int q = lane & 3;                        // this lane's TM-chain gate
  const bool l3 = (lane >> 3) & 1;
  const bool l4 = (lane >> 4) & 1;
  const bool l5 = (lane >> 5) & 1;
  const bool qb0 = q & 1;
  const bool qb1 = (q >> 1) & 1;
  const int D0 = 2 * lane;                       // cell-owned dims D0, D0+1
  const int b = blockIdx.x;

  // ---- one-time register preloads ----
  // z-dot weights, transposed: this lane's dims D0,D0+1 for ALL 8 wires (INV2PI folded)
  float wxx[8], wxy[8], whx[8], why[8];
#pragma unroll
  for (int w = 0; w < 8; ++w) {
    wxx[w] = Wq[w * 256 + D0]       * INV2PI;
    wxy[w] = Wq[w * 256 + D0 + 1]   * INV2PI;
    whx[w] = Wq[w * 256 + 128 + D0] * INV2PI;
    why[w] = Wq[w * 256 + 128 + D0 + 1] * INV2PI;
  }
  const float bqv = bq[r] * INV2PI;

  // per-rotation gate GEMM weights / bias / activation constants:
  // rotation k <-> gate gk=(q+k)&3 at dims D0,D0+1; ksc folded (act = exp2(acc))
  vf2 wgk[8][4]; vf2 biask[4]; float amulk[4], oaddk[4];
#pragma unroll
  for (int k = 0; k < 4; ++k) {
    const int gk = (q + k) & 3;
    const float* W = (gk == 0) ? Wf : (gk == 1) ? Wi : (gk == 2) ? Wg : Wo;
    const float* B = (gk == 0) ? bf : (gk == 1) ? bi : (gk == 2) ? bg : bo;
    const float am = (gk == 2) ? 2.0f : 1.0f;    // tanh = 2*sigmoid(2x)-1
    amulk[k] = am;
    oaddk[k] = (gk == 2) ? -1.0f : 0.0f;
    const float ks = -am * LOG2E;
#pragma unroll
    for (int w = 0; w < 8; ++w) {
      wgk[w][k].x = W[D0 * 8 + w] * ks;
      wgk[w][k].y = W[(D0 + 1) * 8 + w] * ks;
    }
    biask[k].x = B[D0] * ks;
    biask[k].y = B[D0 + 1] * ks;
  }
  // TM constants for OWN gate q
  const float* gP = (q == 0) ? pf : (q == 1) ? pi_ : (q == 2) ? pg : po;
  vf2 cbsb[8]; float C1[8], S1[8];
#pragma unroll
  for (int w = 0; w < 8; ++w) {
    float th0 = gP[w], th1 = gP[8 + w];
    cbsb[w].x = cosf(th0); cbsb[w].y = sinf(th0);
    C1[w] = cosf(th1); S1[w] = sinf(th1);
  }

  // state (all in registers)
  vf2 c2; c2.x = 0.f; c2.y = 0.f;
  vf2 h2v; h2v.x = 0.f; h2v.y = 0.f;
  float xpart[8];

  const float* xgl = X + (size_t)b * IN_DIM + D0;
  float* outp = out + (size_t)b * HID + D0;

  // ---- prologue: xpart(t=0) + X(1) into pipeline buffer A ----
  vf2 xcA, xcB;
  {
    vf2 x0 = *(const vf2*)xgl;                               // X(0), lane's 2 dims
#pragma unroll
    for (int w = 0; w < 8; ++w) xpart[w] = fmaf(x0.x, wxx[w], x0.y * wxy[w]);
    xcA = *(const vf2*)(xgl + (size_t)1 * (BATCH * IN_DIM)); // X(1)
  }

// XC: buffer holding X(T+1), consumed at this step's xpart-tail.
// XL: buffer to fill with X(min(T+2, SEQ-1)).
#define QSTEP(XC, XL, T)                                                              \
  {                                                                                   \
    /* ---- 0. issue X(T+2) load: oldest-consumed-first vmem discipline ---- */       \
    {                                                                                 \
      const int tl_ = ((T) + 2 < SEQ) ? (T) + 2 : (SEQ - 1);                          \
      XL = *(const vf2*)(xgl + (size_t)tl_ * (BATCH * IN_DIM));                       \
    }                                                                                 \
    /* ---- 1. part[w] + butterfly reduce-scatter -> z at lanes r==w ---- */          \
    float part[8];                                                                    \
    _Pragma("unroll")                                                                 \
    for (int w = 0; w < 8; ++w)                                                       \
      part[w] = fmaf(h2v.x, whx[w], fmaf(h2v.y, why[w], xpart[w]));                   \
    float tA[8];                                                                      \
    _Pragma("unroll")                                                                 \
    for (int w = 0; w < 8; ++w) tA[w] = xor32_sum(part[w]);      /* xor32 */          \
    float nB0 = l5 ? tA[4] : tA[0];                                                   \
    float nB1 = l5 ? tA[5] : tA[1];                                                   \
    float nB2 = l5 ? tA[6] : tA[2];                                                   \
    float nB3 = l5 ? tA[7] : tA[3];                                                   \
    float sB0 = swz16(nB0), sB1 = swz16(nB1), sB2 = swz16(nB2), sB3 = swz16(nB3);     \
    /* ---- xpart tail for T+1 (counted vmcnt; fills the swizzle wait) ---- */        \
    _Pragma("unroll")                                                                 \
    for (int w = 0; w < 8; ++w) xpart[w] = fmaf(XC.x, wxx[w], XC.y * wxy[w]);         \
    float tB0 = nB0 + sB0, tB1 = nB1 + sB1, tB2 = nB2 + sB2, tB3 = nB3 + sB3;         \
    float mC0 = l4 ? tB2 : tB0;                                                       \
    float mC1 = l4 ? tB3 : tB1;                                                       \
    float tC0 = mC0 + dpp_mov<0x128>(mC0);                       /* xor8 */           \
    float tC1 = mC1 + dpp_mov<0x128>(mC1);                                            \
    float zr = l3 ? tC1 : tC0;                                                        \
    zr = dpp_add<0xB1>(zr); zr = dpp_add<0x4E>(zr); zr = dpp_add<0x141>(zr);          \
    float zz = zr + bqv;                          /* already in revolutions */        \
    /* ---- 2. sincos + readlane broadcast (lane 8w holds z[w]) ---- */               \
    float szv = sin2pi_f(zz), czv = cos2pi_f(zz);                                     \
    float cqs[8], sqs[8];                                                             \
    _Pragma("unroll")                                                                 \
    for (int w = 0; w < 8; ++w) { cqs[w] = rdlane(czv, 8 * w); sqs[w] = rdlane(szv, 8 * w); } \
    /* ---- 3. TM chain (own gate q) + quad-rotated 4-gate GEMM ---- */               \
    vf2 acc0 = biask[0], acc1 = biask[1], acc2 = biask[2], acc3 = biask[3];           \
    float u_, d_, P_, R_;                                                             \
    {                                                                                 \
      vf2 KA0 = cbsb[0] * cqs[0];                                                     \
      u_ = C1[0]; d_ = C1[0] * KA0.x;                                                 \
      P_ = -S1[0] * KA0.y; R_ = -S1[0] * sqs[0];                                      \
    }                                                                                 \
    _Pragma("unroll")                                                                 \
    for (int w = 1; w < 8; ++w) {                                                     \
      vf2 KA = cbsb[w] * cqs[w];                                                      \
      float K_ = KA.x, A2_ = KA.y, B2_ = sqs[w];                                      \
      float Md = fmaf(A2_, P_, d_);                                                   \
      float MP = fmaf(A2_, d_, P_);                                                   \
      float Mu = fmaf(K_, u_, -(B2_ * R_));                                           \
      float MR = fmaf(B2_, u_, K_ * R_);                                              \
      float e1 = dpp_mov<0x39>(Md);               /* ev of gate q+1 */                \
      float e2 = dpp_mov<0x4E>(Md);               /* ev of gate q+2 */                \
      float e3 = dpp_mov<0x93>(Md);               /* ev of gate q+3 */                \
      acc0 += Md * wgk[w - 1][0];                                                     \
      acc1 += e1 * wgk[w - 1][1];                                                     \
      acc2 += e2 * wgk[w - 1][2];                                                     \
      acc3 += e3 * wgk[w - 1][3];                                                     \
      u_ = C1[w] * Md; d_ = C1[w] * Mu;                                               \
      P_ = -S1[w] * MP; R_ = -S1[w] * MR;                                             \
    }                                                                                 \
    {                                                                                 \
      float ev7_ = d_ + P_;                                                           \
      float e1 = dpp_mov<0x39>(ev7_);                                                 \
      float e2 = dpp_mov<0x4E>(ev7_);                                                 \
      float e3 = dpp_mov<0x93>(ev7_);                                                 \
      acc0 += ev7_ * wgk[7][0];                                                       \
      acc1 += e1 * wgk[7][1];                                                         \
      acc2 += e2 * wgk[7][2];                                                         \
      acc3 += e3 * wgk[7][3];                                                         \
    }                                                                                 \
    /* ---- 4. activation per rotation (bare exp2; per-k amul/oadd) ---- */           \
    vf2 av0, av1, av2, av3;                                                           \
    av0.x = fmaf(rcp_f(1.0f + exp2_f(acc0.x)), amulk[0], oaddk[0]);                   \
    av0.y = fmaf(rcp_f(1.0f + exp2_f(acc0.y)), amulk[0], oaddk[0]);                   \
    av1.x = fmaf(rcp_f(1.0f + exp2_f(acc1.x)), amulk[1], oaddk[1]);                   \
    av1.y = fmaf(rcp_f(1.0f + exp2_f(acc1.y)), amulk[1], oaddk[1]);                   \
    av2.x = fmaf(rcp_f(1.0f + exp2_f(acc2.x)), amulk[2], oaddk[2]);                   \
    av2.y = fmaf(rcp_f(1.0f + exp2_f(acc2.y)), amulk[2], oaddk[2]);                   \
    av3.x = fmaf(rcp_f(1.0f + exp2_f(acc3.x)), amulk[3], oaddk[3]);                   \
    av3.y = fmaf(rcp_f(1.0f + exp2_f(acc3.y)), amulk[3], oaddk[3]);                   \
    /* ---- 5. un-rotate (rotate right by q, 2 conditional levels) ---- */            \
    vf2 b0 = qb0 ? av3 : av0;                                                         \
    vf2 b1 = qb0 ? av0 : av1;                                                         \
    vf2 b2 = qb0 ? av1 : av2;                                                         \
    vf2 b3 = qb0 ? av2 : av3;                                                         \
    vf2 fv = qb1 ? b2 : b0;                                                           \
    vf2 iv = qb1 ? b3 : b1;                                                           \
    vf2 gv = qb1 ? b0 : b2;                                                           \
    vf2 ov = qb1 ? b1 : b3;                                                           \
    /* ---- 6. cell update (lane-local, dims D0, D0+1) ---- */                        \
    c2 = fv * c2 + iv * gv;                                                           \
    h2v.x = ov.x * tanh_f(c2.x);                                                      \
    h2v.y = ov.y * tanh_f(c2.y);                                                      \
    /* ---- 7. output store ---- */                                                   \
    *(vf2*)(outp + (size_t)(T) * (BATCH * HID)) = h2v;                                \
  }

#pragma unroll 1
  for (int tt = 0; tt < SEQ; tt += 2) {
    QSTEP(xcA, xcB, tt);
    QSTEP(xcB, xcA, tt + 1);
  }
#undef QSTEP

  // hx, cx
  {
    size_t base = (size_t)SEQ * BATCH * HID;
    *(vf2*)(out + base + (size_t)b * HID + D0) = h2v;
    *(vf2*)(out + base + (size_t)BATCH * HID + (size_t)b * HID + D0) = c2;
  }
}

extern "C" void kernel_launch(void* const* d_in, const int* in_sizes, int n_in,
                              void* d_out, int out_size, void* d_ws, size_t ws_size,
                              hipStream_t stream) {
  (void)in_sizes; (void)n_in; (void)out_size; (void)d_ws; (void)ws_size;
  const float* X   = (const float*)d_in[0];
  const float* Wq  = (const float*)d_in[1];
  const float* bq  = (const float*)d_in[2];
  const float* pf  = (const float*)d_in[3];
  const float* pi_ = (const float*)d_in[4];
  const float* pg  = (const float*)d_in[5];
  const float* po  = (const float*)d_in[6];
  const float* Wf  = (const float*)d_in[7];
  const float* bf  = (const float*)d_in[8];
  const float* Wi  = (const float*)d_in[9];
  const float* bi  = (const float*)d_in[10];
  const float* Wg  = (const float*)d_in[11];
  const float* bg  = (const float*)d_in[12];
  const float* Wo  = (const float*)d_in[13];
  const float* bo  = (const float*)d_in[14];
  float* out = (float*)d_out;

  qlstm_kernel<<<BATCH, 64, 0, stream>>>(X, Wq, bq, pf, pi_, pg, po,
                                         Wf, bf, Wi, bi, Wg, bg, Wo, bo, out);
}